// Round 1
// baseline (224.690 us; speedup 1.0000x reference)
//
#include <hip/hip_runtime.h>
#include <hip/hip_bf16.h>
#include <cstdint>

#define B_SZ 4
#define T_SZ 2048
#define C_SZ 1024
#define H_SZ 16
#define D_SZ 64
#define BT_SZ (B_SZ * T_SZ)     // 8192
#define C3_SZ (3 * C_SZ)        // 3072
#define NKC (C_SZ / 32)         // 32 K-chunks of 32
#define NKT (C_SZ / 64)         // 16 K-tiles of BK=64

typedef __attribute__((ext_vector_type(8))) short bf16x8;
typedef __attribute__((ext_vector_type(4))) float f32x4;
typedef __attribute__((ext_vector_type(4))) unsigned short ushort4v;
typedef __attribute__((ext_vector_type(4))) unsigned int uint4v;

typedef __attribute__((address_space(3))) unsigned int lds_u32;
typedef __attribute__((address_space(1))) const unsigned int glb_u32;

__device__ __forceinline__ unsigned short f2bf(float f) {
  unsigned u = __builtin_bit_cast(unsigned, f);
  u += 0x7fffu + ((u >> 16) & 1u);  // round-to-nearest-even
  return (unsigned short)(u >> 16);
}

// pack two fp32 -> two bf16 (truncating) in ONE v_perm_b32
__device__ __forceinline__ unsigned packbf2(float lo, float hi) {
  return __builtin_amdgcn_perm(__builtin_bit_cast(unsigned, hi),
                               __builtin_bit_cast(unsigned, lo), 0x07060302u);
}

// async global->LDS, 16B per lane; LDS dest = wave-uniform base + lane*16
__device__ __forceinline__ void gll16(const unsigned short* g,
                                      unsigned short* l) {
  __builtin_amdgcn_global_load_lds((glb_u32*)g, (lds_u32*)l, 16, 0, 0);
}

// ===========================================================================
// Fragment layouts (verified rounds 2-7):
//  A-frag blocked: elem(r,k) -> ((tb*NKC+kc)*4+quad)*128 + (r&15)*8 + (k&7)
//  B-frag blocked: same with n = c&15
//  Vf key-permuted PV B-operand: elem(t,d) -> ((gb*4+dv)*4+quad)*128
//      + (d&15)*8 + j,  kk=t&31, quad=(kk>>2)&3, j=(kk>>4)*4+(kk&3)
//
// NOTE (round 8 lesson): NEVER cap this family of register-heavy MFMA
// kernels with __launch_bounds__ min-waves on gfx950 — the unified
// VGPR/AGPR file makes the compiler split 64/64 and spill the whole
// accumulator to scratch (1.6 GB HBM traffic, 6x slowdown).
// ===========================================================================

// ---------------------------------------------------------------------------
// pack_all: fused pack_x + pack_w(W_attn) + pack_w(W_proj)   (unchanged)
// ---------------------------------------------------------------------------
__device__ __forceinline__ void pack_x_task(const float* __restrict__ x,
                                            unsigned short* __restrict__ Af,
                                            int task, int lane) {
  const int quad = lane >> 4, n = lane & 15;
  const int tb = task >> 5, kc = task & 31;
  const float* src = x + (size_t)(tb * 16 + n) * C_SZ + kc * 32 + quad * 8;
  float4 a = *(const float4*)src;
  float4 b = *(const float4*)(src + 4);
  ushort4v o0, o1;
  o0[0] = f2bf(a.x); o0[1] = f2bf(a.y); o0[2] = f2bf(a.z); o0[3] = f2bf(a.w);
  o1[0] = f2bf(b.x); o1[1] = f2bf(b.y); o1[2] = f2bf(b.z); o1[3] = f2bf(b.w);
  unsigned short* dst = Af + ((size_t)((tb * NKC + kc) * 4 + quad) * 16 + n) * 8;
  *(ushort4v*)dst = o0;
  *(ushort4v*)(dst + 4) = o1;
}

__device__ __forceinline__ void pack_w_task(const float* __restrict__ W,
                                            unsigned short* __restrict__ Wb,
                                            int N, int task, int lane) {
  const int quad = lane >> 4, n = lane & 15;
  const int nt = task >> 5, kc = task & 31;
  const int col = nt * 16 + n;
  const int k0 = kc * 32 + quad * 8;
  ushort4v o0, o1;
#pragma unroll
  for (int i = 0; i < 4; ++i) o0[i] = f2bf(W[(size_t)(k0 + i) * N + col]);
#pragma unroll
  for (int i = 0; i < 4; ++i) o1[i] = f2bf(W[(size_t)(k0 + 4 + i) * N + col]);
  unsigned short* dst = Wb + ((size_t)((nt * NKC + kc) * 4 + quad) * 16 + n) * 8;
  *(ushort4v*)dst = o0;
  *(ushort4v*)(dst + 4) = o1;
}

__global__ __launch_bounds__(256) void pack_all(
    const float* __restrict__ x, const float* __restrict__ Wa,
    const float* __restrict__ Wp, unsigned short* __restrict__ Af,
    unsigned short* __restrict__ Wab, unsigned short* __restrict__ Wpb) {
  const int bx = blockIdx.x;
  const int sub = threadIdx.x >> 6;
  const int lane = threadIdx.x & 63;
  if (bx < 4096) {
    pack_x_task(x, Af, bx * 4 + sub, lane);              // 512 tb x 32 kc
  } else if (bx < 4096 + 1536) {
    pack_w_task(Wa, Wab, C3_SZ, (bx - 4096) * 4 + sub, lane);  // 192 nt x 32
  } else {
    pack_w_task(Wp, Wpb, C_SZ, (bx - 5632) * 4 + sub, lane);   // 64 nt x 32
  }
}

// ---------------------------------------------------------------------------
// 8-phase counted-vmcnt mainloop (round 9): BM=128, BN=256, BK=64,
// 512 threads = 8 waves (2 row x 4 col), per-wave 64x64 output (acc[4][4],
// same per-wave geometry as the old verified 128x128 kernel -> epilogues
// carry over verbatim).
//
// LDS 96 KiB: buffer b at b*24576 shorts {A tile 8192, B tile 16384}.
// A chunk (tb 0..7, kc 0..1) at (tb*2+kc)*512; B chunk (nt 0..15, kc) at
// 8192+(nt*2+kc)*512. Same fragment-blocked image as global -> ds_read_b128
// conflict-free (SQ_LDS_BANK_CONFLICT == 0 on the old kernel), no swizzle.
//
// Schedule (T3+T4+T5). Per tile t (4 phases, 2 barriers each, raw s_barrier
// so global_load_lds stays in flight across barriers):
//   P1: ds_read a(mh0) 4x + b(all 4 nt) 8x | stage A-h1 of t+1 (other buf)
//   P2:                                     | stage B-h0 of t+2 (this buf)
//   P3: ds_read a(mh1) 4x                   | stage B-h1 of t+2
//   P4:                                     | stage A-h0 of t+2, vmcnt(5)
// Overwrite-safety is barrier-proven: B halves last ds_read in P1 (staged
// over in P2/P3, after P1's closing barrier); A-h0 last read P3 (staged P4);
// A-h1 last read P3 (staged next tile's P1). vmcnt math: exactly 5 wave-loads
// are issued after tile t+1's last load (1A + 2B + 2B... = P2..P4), so
// vmcnt(5) at the tile boundary guarantees t+1 resident; extra unrelated
// loads interleaved by the compiler can only over-drain (still correct).
// ---------------------------------------------------------------------------
__device__ __forceinline__ void gemm_8ph_mainloop(
    const unsigned short* __restrict__ A, const unsigned short* __restrict__ B,
    int tbB, int ntB, unsigned short* smem, f32x4 acc[4][4]) {
  const int tid = threadIdx.x;
  const int w = tid >> 6, lane = tid & 63;
  const int quad = lane >> 4, n = lane & 15;
  const int wr = w >> 2, wc = w & 3;

  // per-wave stage assignment: A half = 8 chunks -> 1 load/wave;
  // B half = 16 chunks -> 2 loads/wave.
  auto stageA = [&](int buf, int t, int h) {
    gll16(A + ((size_t)(tbB + h * 4 + (w >> 1)) * NKC + t * 2 + (w & 1)) * 512 +
              lane * 8,
          smem + buf * 24576 + ((h * 4 + (w >> 1)) * 2 + (w & 1)) * 512);
  };
  auto stageB = [&](int buf, int t, int h) {
    const unsigned short* src =
        B + ((size_t)(ntB + h * 8 + w) * NKC + t * 2) * 512 + lane * 8;
    unsigned short* dst = smem + buf * 24576 + 8192 + (h * 8 + w) * 1024;
    gll16(src, dst);
    gll16(src + 512, dst + 512);
  };

  auto ldA = [&](int buf, int mh, bf16x8 af[2][2]) {
#pragma unroll
    for (int mi = 0; mi < 2; ++mi)
#pragma unroll
      for (int kc = 0; kc < 2; ++kc)
        af[mi][kc] = *(const bf16x8*)(smem + buf * 24576 +
            ((wr * 4 + mh * 2 + mi) * 2 + kc) * 512 + quad * 128 + n * 8);
  };
  auto ldB = [&](int buf, bf16x8 bfr[4][2]) {
#pragma unroll
    for (int nn = 0; nn < 4; ++nn)
#pragma unroll
      for (int kc = 0; kc < 2; ++kc)
        bfr[nn][kc] = *(const bf16x8*)(smem + buf * 24576 + 8192 +
            ((wc * 4 + nn) * 2 + kc) * 512 + quad * 128 + n * 8);
  };
  auto mmaQ = [&](int mh, int nh, bf16x8 af[2][2], bf16x8 bfr[4][2]) {
    __builtin_amdgcn_s_setprio(1);
#pragma unroll
    for (int mi = 0; mi < 2; ++mi)
#pragma unroll
      for (int nj = 0; nj < 2; ++nj)
#pragma unroll
        for (int kc = 0; kc < 2; ++kc)
          acc[mh * 2 + mi][nh * 2 + nj] =
              __builtin_amdgcn_mfma_f32_16x16x32_bf16(
                  af[mi][kc], bfr[nh * 2 + nj][kc],
                  acc[mh * 2 + mi][nh * 2 + nj], 0, 0, 0);
    __builtin_amdgcn_s_setprio(0);
  };

  // ---- prologue: tile0 full (6 loads) + tile1 minus A-h1 (5 loads) ----
  stageB(0, 0, 0); stageB(0, 0, 1); stageA(0, 0, 0); stageA(0, 0, 1);
  stageB(1, 1, 0); stageB(1, 1, 1); stageA(1, 1, 0);
  asm volatile("s_waitcnt vmcnt(5)" ::: "memory");  // tile0's 6 landed
  __builtin_amdgcn_s_barrier();

  auto tileStep = [&](int t, int cur, bool s1, bool s2) {
    const int nxt = cur ^ 1;
    bf16x8 af[2][2], bfr[4][2];
    // ---- P1 ----
    ldA(cur, 0, af);
    ldB(cur, bfr);
    if (s1) stageA(nxt, t + 1, 1);
    __builtin_amdgcn_s_barrier();
    mmaQ(0, 0, af, bfr);
    __builtin_amdgcn_s_barrier();
    // ---- P2 ----
    if (s2) stageB(cur, t + 2, 0);
    __builtin_amdgcn_s_barrier();
    mmaQ(0, 1, af, bfr);
    __builtin_amdgcn_s_barrier();
    // ---- P3 ----
    ldA(cur, 1, af);
    if (s2) stageB(cur, t + 2, 1);
    __builtin_amdgcn_s_barrier();
    mmaQ(1, 1, af, bfr);
    __builtin_amdgcn_s_barrier();
    // ---- P4 ----
    if (s2) stageA(cur, t + 2, 0);
    __builtin_amdgcn_s_barrier();
    mmaQ(1, 0, af, bfr);
    if (s2) {
      asm volatile("s_waitcnt vmcnt(5)" ::: "memory");   // tile t+1 resident
    } else if (s1) {
      asm volatile("s_waitcnt vmcnt(0)" ::: "memory");   // epilogue drain
    }
    __builtin_amdgcn_s_barrier();
  };

  for (int t = 0; t < NKT - 2; ++t) tileStep(t, t & 1, true, true);
  tileStep(NKT - 2, (NKT - 2) & 1, true, false);
  tileStep(NKT - 1, (NKT - 1) & 1, false, false);
}

// qkv: grid 768 = 64 by x 12 bx, 3 exact waves of 256 CUs at 1 block/CU.
// XCD-aware swizzle: xcd owns 8 consecutive by rows, bx varies fastest.
__global__ __launch_bounds__(512) void qkv_mfma(
    const unsigned short* __restrict__ Af, const unsigned short* __restrict__ Wab,
    const float* __restrict__ bias, unsigned short* __restrict__ Qf,
    unsigned short* __restrict__ Kf, unsigned short* __restrict__ Vf) {
  __shared__ __align__(16) unsigned short smem[49152];  // 96 KiB
  const int tid = threadIdx.x;
  const int w = tid >> 6, lane = tid & 63;
  const int quad = lane >> 4, n = lane & 15;
  const int wr = w >> 2, wc = w & 3;
  const int f = blockIdx.x;
  const int xcd = f & 7, i = f >> 3;
  const int by = xcd * 8 + (i / 12);   // [0,64)
  const int bx = i % 12;               // [0,12)
  f32x4 acc[4][4];
#pragma unroll
  for (int m = 0; m < 4; ++m)
#pragma unroll
    for (int nn = 0; nn < 4; ++nn) acc[m][nn] = (f32x4){0.f, 0.f, 0.f, 0.f};

  gemm_8ph_mainloop(Af, Wab, by * 8, bx * 16, smem, acc);

  const int cb = bx * 256 + wc * 64;
  const int which = cb >> 10;
  const int h = (cb & 1023) >> 6;
  const int gr0 = by * 128 + wr * 64;
  const int b = gr0 >> 11;
  const int t0 = gr0 & 2047;
  const size_t bhoff = (size_t)(b * H_SZ + h) * (T_SZ * D_SZ);
  float bfl[4];
#pragma unroll
  for (int nn = 0; nn < 4; ++nn) bfl[nn] = bias[cb + nn * 16 + n];

  if (which < 2) {
    unsigned short* dst = ((which == 0) ? Qf : Kf) + bhoff;
    // Q carries 1/sqrt(D) AND log2(e): softmax exp becomes a bare v_exp_f32
    const float scl = (which == 0) ? 0.18033688f : 1.0f;
#pragma unroll
    for (int m = 0; m < 4; ++m) {
      const int tb = (t0 + m * 16) >> 4;
#pragma unroll
      for (int nn = 0; nn < 4; ++nn) {
        const int dc = nn >> 1;
        const int qd = (nn & 1) * 2 + (n >> 3);
        const int jq = n & 7;
#pragma unroll
        for (int r = 0; r < 4; ++r) {
          const int nq = quad * 4 + r;
          dst[((size_t)((tb * 2 + dc) * 4 + qd)) * 128 + nq * 8 + jq] =
              f2bf((acc[m][nn][r] + bfl[nn]) * scl);
        }
      }
    }
  } else {
    unsigned short* dst = Vf + bhoff;
    const int gb0 = t0 >> 5;
#pragma unroll
    for (int m = 0; m < 4; ++m) {
      const int gb = gb0 + (m >> 1);
#pragma unroll
      for (int nn = 0; nn < 4; ++nn) {
#pragma unroll
        for (int r = 0; r < 4; ++r) {
          dst[((size_t)((gb * 4 + nn) * 4 + quad)) * 128 + n * 8 + (m & 1) * 4 + r] =
              f2bf(acc[m][nn][r] + bfl[nn]);
        }
      }
    }
  }
}

// proj: grid 256 = 64 by x 4 bx, exactly one wave of 256 CUs.
__global__ __launch_bounds__(512) void proj_mfma(
    const unsigned short* __restrict__ Yf, const unsigned short* __restrict__ Wpb,
    const float* __restrict__ bias, float* __restrict__ out) {
  __shared__ __align__(16) unsigned short smem[49152];  // 96 KiB
  const int tid = threadIdx.x;
  const int w = tid >> 6, lane = tid & 63;
  const int quad = lane >> 4, n = lane & 15;
  const int wr = w >> 2, wc = w & 3;
  const int f = blockIdx.x;
  const int xcd = f & 7, i = f >> 3;
  const int by = xcd * 8 + (i / 4);    // [0,64)
  const int bx = i % 4;                // [0,4)
  f32x4 acc[4][4];
#pragma unroll
  for (int m = 0; m < 4; ++m)
#pragma unroll
    for (int nn = 0; nn < 4; ++nn) acc[m][nn] = (f32x4){0.f, 0.f, 0.f, 0.f};

  gemm_8ph_mainloop(Yf, Wpb, by * 8, bx * 16, smem, acc);

  const int cb = bx * 256 + wc * 64;
  const int gr0 = by * 128 + wr * 64;
  float bfl[4];
#pragma unroll
  for (int nn = 0; nn < 4; ++nn) bfl[nn] = bias[cb + nn * 16 + n];
#pragma unroll
  for (int m = 0; m < 4; ++m)
#pragma unroll
    for (int nn = 0; nn < 4; ++nn)
#pragma unroll
      for (int r = 0; r < 4; ++r)
        out[(size_t)(gr0 + m * 16 + quad * 4 + r) * C_SZ + cb + nn * 16 + n] =
            acc[m][nn][r] + bfl[nn];
}

// ---------------------------------------------------------------------------
// attn_mfma v7 (unchanged): K/V register prefetch, no launch_bounds cap.
// ---------------------------------------------------------------------------
__global__ __launch_bounds__(64) void attn_mfma(
    const unsigned short* __restrict__ Qf,
    const unsigned short* __restrict__ Kf,
    const unsigned short* __restrict__ Vf, unsigned short* __restrict__ Yf) {
  const int lane = threadIdx.x;
  const int quad = lane >> 4;
  const int n = lane & 15;
  const int bx = blockIdx.x;
  const int qt = 31 - (bx >> 6);  // long blocks dispatch first
  const int bh = bx & 63;
  const int b = bh >> 4, h = bh & 15;
  const int wq0 = qt * 64;
  const size_t bhoff = (size_t)bh * (T_SZ * D_SZ);
  const bf16x8* Qp = (const bf16x8*)(Qf + bhoff);
  const bf16x8* Kp = (const bf16x8*)(Kf + bhoff);
  const bf16x8* Vp = (const bf16x8*)(Vf + bhoff);

  bf16x8 qfr[4][2];
#pragma unroll
  for (int m = 0; m < 4; ++m) {
    const int tb = (wq0 >> 4) + m;
#pragma unroll
    for (int dc = 0; dc < 2; ++dc)
      qfr[m][dc] = Qp[((tb * 2 + dc) * 4 + quad) * 16 + n];
  }

  bf16x8 kfr[4][2], vfr[2][4];
  f32x4 O[4][4];
  f32x4 ls[4];
#pragma unroll
  for (int m = 0; m < 4; ++m) {
    ls[m] = (f32x4){0.f, 0.f, 0.f, 0.f};
#pragma unroll
    for (int dv = 0; dv < 4; ++dv) O[m][dv] = (f32x4){0.f, 0.f, 0.f, 0.f};
  }

  // preload K and V for tile 0
#pragma unroll
  for (int s = 0; s < 4; ++s) {
    kfr[s][0] = Kp[((s * 2 + 0) * 4 + quad) * 16 + n];
    kfr[s][1] = Kp[((s * 2 + 1) * 4 + quad) * 16 + n];
  }
#pragma unroll
  for (int g = 0; g < 2; ++g)
#pragma unroll
    for (int dv = 0; dv < 4; ++dv)
      vfr[g][dv] = Vp[((g * 4 + dv) * 4 + quad) * 16 + n];

  // ---- full (unmasked) k-tiles ----
  for (int kt = 0; kt < qt; ++kt) {
#pragma unroll
    for (int m = 0; m < 4; ++m) {
      f32x4 st[4];
#pragma unroll
      for (int s = 0; s < 4; ++s) {
        f32x4 z = {0.f, 0.f, 0.f, 0.f};
        z = __builtin_amdgcn_mfma_f32_16x16x32_bf16(kfr[s][0], qfr[m][0], z, 0, 0, 0);
        z = __builtin_amdgcn_mfma_f32_16x16x32_bf16(kfr[s][1], qfr[m][1], z, 0, 0, 0);
        st[s] = z;
      }
      if (m == 3) {
        // kfr dead for this tile: prefetch K for tile kt+1 (maybe diagonal)
        const int tb0 = (kt + 1) * 4;
#pragma unroll
        for (int s = 0; s < 4; ++s) {
          kfr[s][0] = Kp[(((tb0 + s) * 2 + 0) * 4 + quad) * 16 + n];
          kfr[s][1] = Kp[(((tb0 + s) * 2 + 1) * 4 + quad) * 16 + n];
        }
      }
      uint4v pw[2];
#pragma unroll
      for (int s = 0; s < 4; ++s) {
        float pr[4];
#pragma unroll
        for (int r = 0; r < 4; ++r) {
          pr[r] = __builtin_amdgcn_exp2f(st[s][r]);
          ls[m][r] += pr[r];
        }
        pw[s >> 1][(s & 1) * 2 + 0] = packbf2(pr[0], pr[1]);
        pw[s >> 1][(s & 1) * 2 + 1] = packbf2(pr[2], pr[3]);
      }
#pragma unroll
      for (int g = 0; g < 2; ++g) {
        const bf16x8 pg = __builtin_bit_cast(bf16x8, pw[g]);
#pragma unroll
        for (int dv = 0; dv < 4; ++dv)
          O[m][dv] = __builtin_amdgcn_mfma_f32_16x16x32_bf16(
              pg, vfr[g][dv], O[m][dv], 0, 0, 0);
      }
      if (m == 3) {
        // vfr dead after this tile's last PV: prefetch V for tile kt+1
        const int gb0 = (kt + 1) * 2;
#pragma unroll
        for (int g = 0; g < 2; ++g)
#pragma unroll
          for (int dv = 0; dv < 4; ++dv)
            vfr[g][dv] = Vp[(((gb0 + g) * 4 + dv) * 4 + quad) * 16 + n];
      }
    }
  }

  // ---- diagonal k-tile (kt == qt): kfr/vfr already resident ----
  {
#pragma unroll
    for (int m = 0; m < 4; ++m) {
      f32x4 st[4];
#pragma unroll
      for (int s = 0; s < 4; ++s) {
        f32x4 z = {0.f, 0.f, 0.f, 0.f};
        if (s <= m) {
          z = __builtin_amdgcn_mfma_f32_16x16x32_bf16(kfr[s][0], qfr[m][0], z, 0, 0, 0);
          z = __builtin_amdgcn_mfma_f32_16x16x32_bf16(kfr[s][1], qfr[m][1], z, 0, 0, 0);
        }
        st[s] = z;
      }
      uint4v pw[2] = {(uint4v){0, 0, 0, 0}, (uint4v){0, 0, 0, 0}};
#pragma unroll
      for (int s = 0; s < 4; ++s) {
        if (s <= m) {
          float pr[4];
#pragma unroll
          for (int r = 0; r < 4; ++r) {
            float v = st[s][r];
            if (s == m && quad * 4 + r > n) v = -1e30f;  // key > query
            pr[r] = __builtin_amdgcn_exp2f(v);
            ls[m][r] += pr[r];
          }
          pw[s >> 1][(s & 1) * 2 + 0] = packbf2(pr[0], pr[1]);
          pw[s >> 1][(s & 1) * 2 + 1] = packbf2(pr[2], pr[3]);
        }
      }
#pragma unroll
      for (int g = 0; g < 2; ++g) {
        if (g * 2 <= m) {
          const bf16x8 pg = __builtin_bit_cast(bf16x8, pw[g]);
#pragma unroll
          for (int dv = 0; dv < 4; ++dv)
            O[m][dv] = __builtin_amdgcn_mfma_f32_16x16x32_bf16(
                pg, vfr[g][dv], O[m][dv], 0, 0, 0);
        }
      }
    }
  }

  // ---- single deferred row-sum reduction + epilogue (bf16 A-frag Yf) ----
#pragma unroll
  for (int m = 0; m < 4; ++m) {
    float lt = ls[m][0] + ls[m][1] + ls[m][2] + ls[m][3];
    lt += __shfl_xor(lt, 16);
    lt += __shfl_xor(lt, 32);
    const float inv = 1.0f / lt;
    float iv[4];
#pragma unroll
    for (int r = 0; r < 4; ++r) iv[r] = __shfl(inv, quad * 4 + r);
    const int tb = (b * T_SZ + wq0 + m * 16) >> 4;
#pragma unroll
    for (int dv = 0; dv < 4; ++dv) {
      const int kc = h * 2 + (dv >> 1);
      const int qa = (dv & 1) * 2 + (n >> 3);
      const int ja = n & 7;
#pragma unroll
      for (int r = 0; r < 4; ++r) {
        const int na = quad * 4 + r;
        Yf[((size_t)((tb * NKC + kc) * 4 + qa)) * 128 + na * 8 + ja] =
            f2bf(O[m][dv][r] * iv[r]);
      }
    }
  }
}

// ---------------------------------------------------------------------------
extern "C" void kernel_launch(void* const* d_in, const int* in_sizes, int n_in,
                              void* d_out, int out_size, void* d_ws,
                              size_t ws_size, hipStream_t stream) {
  const float* x = (const float*)d_in[0];
  const float* W_attn = (const float*)d_in[1];
  const float* b_attn = (const float*)d_in[2];
  const float* W_proj = (const float*)d_in[3];
  const float* b_proj = (const float*)d_in[4];
  float* out = (float*)d_out;

  const size_t perbf = (size_t)B_SZ * H_SZ * T_SZ * D_SZ;  // 8M elems
  unsigned short* Af = (unsigned short*)d_ws;              // 16 MB
  unsigned short* Wab = Af + (size_t)BT_SZ * C_SZ;         // 6 MB
  unsigned short* Wpb = Wab + (size_t)C_SZ * C3_SZ;        // 2 MB
  unsigned short* Qf = Wpb + (size_t)C_SZ * C_SZ;          // 16 MB
  unsigned short* Kf = Qf + perbf;                         // 16 MB
  unsigned short* Vf = Kf + perbf;                         // 16 MB
  unsigned short* Yf = Vf + perbf;                         // 16 MB

  pack_all<<<6144, 256, 0, stream>>>(x, W_attn, W_proj, Af, Wab, Wpb);
  qkv_mfma<<<768, 512, 0, stream>>>(Af, Wab, b_attn, Qf, Kf, Vf);
  attn_mfma<<<dim3(32 * B_SZ * H_SZ), 64, 0, stream>>>(Qf, Kf, Vf, Yf);
  proj_mfma<<<256, 512, 0, stream>>>(Yf, Wpb, b_proj, out);
}